// Round 3
// baseline (94.908 us; speedup 1.0000x reference)
//
#include <hip/hip_runtime.h>
#include <math.h>

// Shapes: S=4 B=8 N=2048 K=16 D=32 H=128; SBN=65536 rows; 2048 rows per sb.
#define EXP2F(x) __builtin_amdgcn_exp2f(x)
#define RCPF(x)  __builtin_amdgcn_rcpf(x)
#define C_SCALE 2.8853900817779268f   // 2*log2(e): tanh(z) = 1 - 2/(1+2^(c*z))

// ---------------------------------------------------------------------------
// prep: ek[(sb*16+k)*128+h] = exp2(c*(mu@Wm + tau@Wt + b1))  (f32, 256 KB ws)
//       w2f[h] = -2*W2[h]
// ---------------------------------------------------------------------------
__global__ __launch_bounds__(256) void prep_kernel(
    const float* __restrict__ mu, const float* __restrict__ tau,
    const float* __restrict__ W1, const float* __restrict__ b1,
    const float* __restrict__ W2,
    float* __restrict__ ek, float* __restrict__ w2f) {
  int g = blockIdx.x * 256 + threadIdx.x;   // 0..65535
  int h = g & 127, row = g >> 7;            // row = sb*16+k (512 rows)
  const float* mur  = mu  + row * 32;
  const float* taur = tau + row * 32;
  float acc = b1[h];
#pragma unroll
  for (int d = 0; d < 32; ++d) {
    acc = fmaf(mur[d],  W1[(32 + d) * 128 + h], acc);   // Wm
    acc = fmaf(taur[d], W1[(64 + d) * 128 + h], acc);   // Wt
  }
  ek[g] = EXP2F(C_SCALE * acc);
  if (g < 128) w2f[g] = -2.0f * W2[g];
}

// ---------------------------------------------------------------------------
// fused main: 32 n-rows per block, all-f32 LDS, aliased regions.
//  phase 1: sEx[r][h] = exp2(c * x[r,:]@Wx[:,h])
//  phase 2: gamma[r][k] = sum_h w2f[h]*rcp(1 + sEx[r][h]*sEk[k][h]); softmax_k
// LDS (words): [0,4224) sW -> later sEk(2112)+sW2(@2112); [4224,5376) sX;
//              [5376,9600) sEx.  Total 38400 B -> 4 blocks/CU.
// ---------------------------------------------------------------------------
__global__ __launch_bounds__(256, 4) void main_kernel(
    const float* __restrict__ x, const float* __restrict__ W1,
    const float* __restrict__ ek, const float* __restrict__ w2f,
    float* __restrict__ out) {
  __shared__ __align__(16) float lds[9600];
  float* sW  = lds;            // 32 x 132 (phase 1)
  float* sX  = lds + 4224;     // 32 x 36
  float* sEx = lds + 5376;     // 32 x 132
  float* sEk = lds;            // 16 x 132 (phase 2, aliases sW)
  float* sW2 = lds + 2112;     // 128      (phase 2, aliases sW)

  int t = threadIdx.x;
  int row0 = blockIdx.x * 32;
  int sb = row0 >> 11;

  // ---- register-stage ek (8 f32/thread, coalesced 32B) and w2 ----
  const float4* eksb = (const float4*)(ek + (size_t)sb * 2048);
  float4 ekr0 = eksb[t * 2];
  float4 ekr1 = eksb[t * 2 + 1];
  float w2r = (t < 128) ? w2f[t] : 0.f;

  // ---- stage x tile: 32x32 = 256 float4, 1/thread, coalesced ----
  {
    float4 v = ((const float4*)(x + (size_t)row0 * 32))[t];
    int n = t >> 3, d4 = t & 7;
    *(float4*)&sX[n * 36 + d4 * 4] = v;
  }
  // ---- stage c*Wx: 32x128 = 1024 float4, 4/thread ----
  {
    const float4* w4 = (const float4*)W1;   // rows 0..31 are Wx
#pragma unroll
    for (int i = 0; i < 4; ++i) {
      int j = i * 256 + t;
      int d = j >> 5, h4 = j & 31;
      float4 v = w4[j];
      v.x *= C_SCALE; v.y *= C_SCALE; v.z *= C_SCALE; v.w *= C_SCALE;
      *(float4*)&sW[d * 132 + h4 * 4] = v;
    }
  }
  __syncthreads();

  // ---- phase 1: 4 rows x 4 h-cols (h stride 32 -> bank-conflict-free) ----
  {
    int rg = t >> 5, hg = t & 31;
    int r0 = rg * 4;
    float acc[4][4] = {{0.f}};
#pragma unroll 8
    for (int d = 0; d < 32; ++d) {
      float wv0 = sW[d * 132 + hg];
      float wv1 = sW[d * 132 + hg + 32];
      float wv2 = sW[d * 132 + hg + 64];
      float wv3 = sW[d * 132 + hg + 96];
#pragma unroll
      for (int i = 0; i < 4; ++i) {
        float xv = sX[(r0 + i) * 36 + d];
        acc[i][0] = fmaf(xv, wv0, acc[i][0]);
        acc[i][1] = fmaf(xv, wv1, acc[i][1]);
        acc[i][2] = fmaf(xv, wv2, acc[i][2]);
        acc[i][3] = fmaf(xv, wv3, acc[i][3]);
      }
    }
#pragma unroll
    for (int i = 0; i < 4; ++i) {
      sEx[(r0 + i) * 132 + hg]      = EXP2F(acc[i][0]);
      sEx[(r0 + i) * 132 + hg + 32] = EXP2F(acc[i][1]);
      sEx[(r0 + i) * 132 + hg + 64] = EXP2F(acc[i][2]);
      sEx[(r0 + i) * 132 + hg + 96] = EXP2F(acc[i][3]);
    }
  }
  __syncthreads();

  // ---- drop staged ek/w2 into the (now dead) sW region ----
  {
    int kk = t >> 4, col = (t & 15) * 8;
    *(float4*)&sEk[kk * 132 + col]     = ekr0;
    *(float4*)&sEk[kk * 132 + col + 4] = ekr1;
    if (t < 128) sW2[t] = w2r;
  }
  __syncthreads();

  // ---- phase 2: 1 row x 2 k per thread, zero conversions ----
  int k2 = t & 7, r = t >> 3;          // r 0..31, k = 2*k2, 2*k2+1
  int k0 = k2 * 2;
  const float* exr  = &sEx[r * 132];
  const float* ekp0 = &sEk[k0 * 132];
  const float* ekp1 = &sEk[(k0 + 1) * 132];
  float a0 = 0.f, a1 = 0.f;
#pragma unroll 4
  for (int h4 = 0; h4 < 32; ++h4) {
    float4 e  = *(const float4*)&exr[h4 * 4];
    float4 f0 = *(const float4*)&ekp0[h4 * 4];
    float4 f1 = *(const float4*)&ekp1[h4 * 4];
    float4 w  = *(const float4*)&sW2[h4 * 4];
    a0 = fmaf(w.x, RCPF(fmaf(e.x, f0.x, 1.f)), a0);
    a1 = fmaf(w.x, RCPF(fmaf(e.x, f1.x, 1.f)), a1);
    a0 = fmaf(w.y, RCPF(fmaf(e.y, f0.y, 1.f)), a0);
    a1 = fmaf(w.y, RCPF(fmaf(e.y, f1.y, 1.f)), a1);
    a0 = fmaf(w.z, RCPF(fmaf(e.z, f0.z, 1.f)), a0);
    a1 = fmaf(w.z, RCPF(fmaf(e.z, f1.z, 1.f)), a1);
    a0 = fmaf(w.w, RCPF(fmaf(e.w, f0.w, 1.f)), a0);
    a1 = fmaf(w.w, RCPF(fmaf(e.w, f1.w, 1.f)), a1);
  }

  // ---- softmax over 16 k = 2 in-thread x 8 lanes (shuffle width 8) ----
  const float l2e = 1.4426950408889634f;
  float m = fmaxf(a0, a1);
#pragma unroll
  for (int s = 1; s < 8; s <<= 1) m = fmaxf(m, __shfl_xor(m, s, 8));
  float p0 = EXP2F((a0 - m) * l2e), p1 = EXP2F((a1 - m) * l2e);
  float sum = p0 + p1;
#pragma unroll
  for (int s = 1; s < 8; s <<= 1) sum += __shfl_xor(sum, s, 8);
  float inv = RCPF(sum);
  *(float2*)&out[(size_t)(row0 + r) * 16 + k0] = make_float2(p0 * inv, p1 * inv);
}

// ---------------------------------------------------------------------------
extern "C" void kernel_launch(void* const* d_in, const int* in_sizes, int n_in,
                              void* d_out, int out_size, void* d_ws, size_t ws_size,
                              hipStream_t stream) {
  const float* x   = (const float*)d_in[0];
  const float* mu  = (const float*)d_in[1];
  const float* tau = (const float*)d_in[2];
  const float* W1  = (const float*)d_in[3];
  const float* b1  = (const float*)d_in[4];
  const float* W2  = (const float*)d_in[5];
  // b2 (d_in[6]) and sum(W2) are k-uniform -> cancelled by softmax.
  float* out = (float*)d_out;

  float* ek  = (float*)d_ws;            // 512*128 f32 = 256 KB
  float* w2f = ek + 512 * 128;          // 128 f32
  (void)in_sizes; (void)n_in; (void)out_size; (void)ws_size;

  prep_kernel<<<256, 256, 0, stream>>>(mu, tau, W1, b1, W2, ek, w2f);
  main_kernel<<<2048, 256, 0, stream>>>(x, W1, ek, w2f, out);
}